// Round 5
// baseline (206.049 us; speedup 1.0000x reference)
//
#include <hip/hip_runtime.h>
#include <hip/hip_bf16.h>

typedef unsigned int u32;
typedef unsigned short u16;
typedef unsigned long long u64;
typedef __attribute__((ext_vector_type(8))) short short8;
typedef __attribute__((ext_vector_type(4))) float f32x4;

#define BATCH 4
#define SEQ   4096
#define DIM   768
#define HD    64
#define NROW  (BATCH*SEQ)   // 16384
#define LOG2E 1.44269504088896f
#define SSCALE (0.125f * LOG2E)
#define NEGBIG (-1.0e30f)
#define MINIT  (-1.0e20f)
#define PSLOT  1056          // floats per partial slot: 1024 O + 16 m + 16 l

__device__ __forceinline__ float ex2(float x) {         // 2^x via v_exp_f32
    return __builtin_amdgcn_exp2f(x);
}
__device__ __forceinline__ u16 f2bf(float f) {          // round-half-up (sub-ulp vs RNE)
    return (u16)((__float_as_uint(f) + 0x8000u) >> 16);
}
__device__ __forceinline__ u32 pkbf(float a, float b) { // pack 2 bf16, 3 VALU ops
    u32 xa = __float_as_uint(a) + 0x8000u;
    u32 xb = __float_as_uint(b) + 0x8000u;
    return __builtin_amdgcn_perm(xb, xa, 0x07060302);   // lo16=bf(a), hi16=bf(b)
}
// Deterministic per-wave dtype sniff: low halves of x's first 64 words look like
// bf16 N(0,1) exponents iff x is packed bf16. Same answer in every wave/block.
__device__ __forceinline__ int sniff_bf16(const u32* x) {
    u32 w = x[threadIdx.x & 63];
    u32 lo = w & 0xffffu;
    u32 e  = (lo >> 7) & 0xffu;
    bool ok = (lo == 0u) || (e >= 96u && e <= 134u);
    u64 bal = __ballot(ok);
    return (__popcll(bal) >= 48) ? 1 : 0;
}

// ---------------- prep: W pack (bids 0..575) + mask bit-pack (576..577) ------
__global__ __launch_bounds__(256) void prep_kernel(
    const u32* __restrict__ xs,
    const void* __restrict__ wq, const void* __restrict__ wk,
    const void* __restrict__ wv, const int* __restrict__ mask,
    u16* __restrict__ wcat, u32* __restrict__ mb)
{
    const int flag = sniff_bf16(xs);
    const int bid = blockIdx.x;
    const int t = threadIdx.x;
    if (bid < 576) {
        const int n  = bid % 192;
        const int kk = (bid / 192) * 256 + t;
        const void* src = (n < 64) ? wq : (n < 128) ? wk : wv;
        const int rr = n & 63;
        u16 o = flag ? ((const u16*)src)[rr * DIM + kk]
                     : f2bf(((const float*)src)[rr * DIM + kk]);
        wcat[n * DIM + kk] = o;
    } else {
        const int wi = (bid - 576) * 256 + t;   // 0..511
        u32 v = 0;
        const int base = wi * 32;
#pragma unroll
        for (int i = 0; i < 32; ++i)
            if (mask[base + i] != 0) v |= (1u << i);
        mb[wi] = v;
    }
}

// ---------------- QKV projection (MFMA, X register-prefetch) ----------------
__global__ __launch_bounds__(256) void qkv_kernel(
    const void* __restrict__ x, const u16* __restrict__ wcat,
    u16* __restrict__ qws, u16* __restrict__ kws, u16* __restrict__ vTws)
{
    const int flag = sniff_bf16((const u32*)x);
    __shared__ u16 Xt[32 * 64];     // chunk-swizzled (16B chunks, chunk^=(row&7))
    __shared__ u16 Vt[32][66];      // v staging for transpose out

    const int t  = threadIdx.x;
    const int l  = t & 63;
    const int w  = t >> 6;
    const int li = l & 15;
    const int g  = l >> 4;
    const int strip = w & 1;
    const int nhalf = w >> 1;
    const int m0 = blockIdx.x * 32;
    const int b  = m0 >> 12;

    f32x4 acc[6];
#pragma unroll
    for (int i = 0; i < 6; ++i) acc[i] = (f32x4){0.f, 0.f, 0.f, 0.f};

    const int srow = t >> 3;   // staging row 0..31
    const int sc   = t & 7;    // staging 16B chunk 0..7
    const int sdst = srow * 64 + ((sc ^ (srow & 7)) * 8);
    const long xoff = (long)(m0 + srow) * DIM + sc * 8;

    auto loadX = [&](int kc) -> short8 {
        if (flag) {
            return *reinterpret_cast<const short8*>((const u16*)x + xoff + kc * 64);
        } else {
            const float* xp = (const float*)x + xoff + kc * 64;
            float4 a = *reinterpret_cast<const float4*>(xp);
            float4 c = *reinterpret_cast<const float4*>(xp + 4);
            union { u32 u[4]; short8 s; } un;
            un.u[0] = pkbf(a.x, a.y); un.u[1] = pkbf(a.z, a.w);
            un.u[2] = pkbf(c.x, c.y); un.u[3] = pkbf(c.z, c.w);
            return un.s;
        }
    };

    short8 xr = loadX(0);
    for (int kc = 0; kc < 12; ++kc) {
        __syncthreads();
        *reinterpret_cast<short8*>(&Xt[sdst]) = xr;
        if (kc < 11) xr = loadX(kc + 1);          // prefetch next tile into regs
        __syncthreads();
        const int arow = strip * 16 + li;
        short8 af0 = *reinterpret_cast<const short8*>(&Xt[arow * 64 + ((g       ^ (arow & 7)) * 8)]);
        short8 af1 = *reinterpret_cast<const short8*>(&Xt[arow * 64 + (((4 + g) ^ (arow & 7)) * 8)]);
        const int kk0 = kc * 64;
#pragma unroll
        for (int ns = 0; ns < 6; ++ns) {
            const u16* wr = wcat + (long)(nhalf * 96 + ns * 16 + li) * DIM + kk0 + g * 8;
            short8 b0 = *reinterpret_cast<const short8*>(wr);
            short8 b1 = *reinterpret_cast<const short8*>(wr + 32);
            acc[ns] = __builtin_amdgcn_mfma_f32_16x16x32_bf16(af0, b0, acc[ns], 0, 0, 0);
            acc[ns] = __builtin_amdgcn_mfma_f32_16x16x32_bf16(af1, b1, acc[ns], 0, 0, 0);
        }
    }

    // epilogue: C row = m0 + strip*16 + 4g + r, col n = nhalf*96 + ns*16 + li
#pragma unroll
    for (int ns = 0; ns < 6; ++ns) {
        const int n = nhalf * 96 + ns * 16 + li;
#pragma unroll
        for (int r = 0; r < 4; ++r) {
            const int rowl = strip * 16 + 4 * g + r;
            u16 bv = f2bf(acc[ns][r]);
            if (n < 64)        qws[(long)(m0 + rowl) * HD + n]        = bv;
            else if (n < 128)  kws[(long)(m0 + rowl) * HD + (n - 64)] = bv;
            else               Vt[rowl][n - 128]                      = bv;
        }
    }
    __syncthreads();
    // transpose v out: vT[(b*64+d)][ (m0&4095) + mg*8 .. +7 ]
    {
        const int d  = t >> 2;   // 0..63
        const int mg = t & 3;    // 0..3
        union { u16 h[8]; short8 s; } u;
#pragma unroll
        for (int i = 0; i < 8; ++i) u.h[i] = Vt[mg * 8 + i][d];
        u16* dst = vTws + ((long)(b * 64 + d)) * SEQ + (m0 & (SEQ - 1)) + mg * 8;
        *reinterpret_cast<short8*>(dst) = u.s;
    }
}

// ---------------- Flash attention (MFMA, split-K, K-prefetch) ----------------
// Unit u (bid>>2): u<256 -> qt16=255-(u>>1), chunk c=u&1 (long tiles, 2 chunks
// of 32 key-tiles); u>=256 -> qt16=383-u, c=0 (single chunk). 4 waves stride kt
// within the chunk. exp2-domain softmax with additive -1e30 mask bias and m
// floor -1e20 (dead tiles/rows degrade to p=0 with no per-element cndmask).
// l computed by MFMA against a ones-fragment. nc==2 writes unnormalized
// partials, merged by merge_kernel.
__global__ __launch_bounds__(256) void attn_kernel(
    const u32* __restrict__ xs,
    const u16* __restrict__ qw, const u16* __restrict__ kw,
    const u16* __restrict__ vTw, const u32* __restrict__ maskbits,
    float* __restrict__ part, void* __restrict__ out)
{
    __shared__ float Ow[4][16][64];
    __shared__ float mwS[4][16];
    __shared__ float lwS[4][16];
    __shared__ __align__(16) u16 Ps[4][16][80];  // per-wave P^T staging (4-way max)

    const int flag = sniff_bf16(xs);
    const int t  = threadIdx.x;
    const int l  = t & 63;
    const int w  = t >> 6;
    const int li = l & 15;
    const int g  = l >> 4;
    const int g4 = g * 4;

    const int bid = blockIdx.x;
    const int b   = bid & 3;
    const int u   = bid >> 2;
    int qt16, c;
    if (u < 256) { qt16 = 255 - (u >> 1); c = u & 1; }
    else         { qt16 = 383 - u;        c = 0;     }
    const int q0    = qt16 * 16;
    const int nkt   = (qt16 >> 2) + 1;
    const int ktBeg = c * 32;
    const int ktEnd = min(ktBeg + 32, nkt);
    const int nc    = (qt16 >= 128) ? 2 : 1;

    // Q fragments (B-operand): lane holds Q[q0+li][g*8+j (+32)]
    const u16* qrow = qw + ((long)(b * SEQ + q0 + li)) * HD + g * 8;
    short8 qf0 = *reinterpret_cast<const short8*>(qrow);
    short8 qf1 = *reinterpret_cast<const short8*>(qrow + 32);

    short8 ones;
#pragma unroll
    for (int i = 0; i < 8; ++i) ones[i] = (short)0x3F80;  // bf16 1.0

    f32x4 O[4];
#pragma unroll
    for (int i = 0; i < 4; ++i) O[i] = (f32x4){0.f, 0.f, 0.f, 0.f};
    f32x4 l4 = (f32x4){0.f, 0.f, 0.f, 0.f};
    float m_run = MINIT;
    const int qg = q0 + li;
    const f32x4 z4 = (f32x4){0.f, 0.f, 0.f, 0.f};

    const u16* kbase = kw  + ((long)(b * SEQ) + li) * HD + g * 8;
    const u16* vbase = vTw + ((long)(b * HD)  + li) * SEQ + g * 8;

    int kt = ktBeg + w;
    short8 ka[8];                       // current K tile frags [sub*2+half]
    if (kt < ktEnd) {
        const u16* kp = kbase + (long)(kt * 64) * HD;
#pragma unroll
        for (int sub = 0; sub < 4; ++sub) {
            ka[2*sub]   = *reinterpret_cast<const short8*>(kp + sub * 16 * HD);
            ka[2*sub+1] = *reinterpret_cast<const short8*>(kp + sub * 16 * HD + 32);
        }
    }

    for (; kt < ktEnd; kt += 4) {
        const int k0 = kt * 64;
        short8 kb[8];
        const int ktn = kt + 4;
        if (ktn < ktEnd) {              // prefetch next K tile
            const u16* kp = kbase + (long)(ktn * 64) * HD;
#pragma unroll
            for (int sub = 0; sub < 4; ++sub) {
                kb[2*sub]   = *reinterpret_cast<const short8*>(kp + sub * 16 * HD);
                kb[2*sub+1] = *reinterpret_cast<const short8*>(kp + sub * 16 * HD + 32);
            }
        }
        const u32 mb0 = maskbits[b * 128 + (k0 >> 5)];
        const u32 mb1 = maskbits[b * 128 + (k0 >> 5) + 1];

        // S^T: A = K subtile (m=key), B = Q; element (sub,r) = key k0+16sub+4g+r, query qg
        float sv[4][4];
#pragma unroll
        for (int sub = 0; sub < 4; ++sub) {
            f32x4 a = __builtin_amdgcn_mfma_f32_16x16x32_bf16(ka[2*sub],   qf0, z4, 0, 0, 0);
            a       = __builtin_amdgcn_mfma_f32_16x16x32_bf16(ka[2*sub+1], qf1, a,  0, 0, 0);
            const u32 word = (sub & 2) ? mb1 : mb0;
#pragma unroll
            for (int r = 0; r < 4; ++r) {
                const int kloc = sub * 16 + g4 + r;
                const bool keep = ((k0 + kloc) <= qg) &&
                                  (((word >> ((sub & 1) * 16 + g4 + r)) & 1u) != 0u);
                sv[sub][r] = fmaf(a[r], SSCALE, keep ? 0.f : NEGBIG);
            }
        }
        float mt = sv[0][0];
#pragma unroll
        for (int sub = 0; sub < 4; ++sub)
#pragma unroll
            for (int r = 0; r < 4; ++r) mt = fmaxf(mt, sv[sub][r]);
        mt = fmaxf(mt, __shfl_xor(mt, 16, 64));
        mt = fmaxf(mt, __shfl_xor(mt, 32, 64));
        const float mnew  = fmaxf(m_run, mt);     // floor MINIT: dead tiles keep m_run
        const float alpha = ex2(m_run - mnew);
        m_run = mnew;

        // p = exp2(sv - mnew) (dead -> underflow to 0), pack to LDS in C-layout
#pragma unroll
        for (int sub = 0; sub < 4; ++sub) {
            float p0 = ex2(sv[sub][0] - mnew);
            float p1 = ex2(sv[sub][1] - mnew);
            float p2 = ex2(sv[sub][2] - mnew);
            float p3 = ex2(sv[sub][3] - mnew);
            uint2 pk = make_uint2(pkbf(p0, p1), pkbf(p2, p3));
            *reinterpret_cast<uint2*>(&Ps[w][li][sub * 16 + g4]) = pk;
        }
        short8 A1 = *reinterpret_cast<const short8*>(&Ps[w][li][g * 8]);
        short8 A2 = *reinterpret_cast<const short8*>(&Ps[w][li][32 + g * 8]);

        // l for rows 4g+r via ones-MFMA (consistent with bf16 P used for O)
        f32x4 lt = __builtin_amdgcn_mfma_f32_16x16x32_bf16(A1, ones, z4, 0, 0, 0);
        lt       = __builtin_amdgcn_mfma_f32_16x16x32_bf16(A2, ones, lt, 0, 0, 0);

        float ar[4];
#pragma unroll
        for (int r = 0; r < 4; ++r) ar[r] = __shfl(alpha, g4 + r, 64);
#pragma unroll
        for (int r = 0; r < 4; ++r) l4[r] = l4[r] * ar[r] + lt[r];
#pragma unroll
        for (int ds = 0; ds < 4; ++ds)
#pragma unroll
            for (int r = 0; r < 4; ++r) O[ds][r] *= ar[r];

        // PV: O[ds] += P * V
#pragma unroll
        for (int ds = 0; ds < 4; ++ds) {
            const u16* vr = vbase + (long)(ds * 16) * SEQ + k0;
            short8 vf0 = *reinterpret_cast<const short8*>(vr);
            short8 vf1 = *reinterpret_cast<const short8*>(vr + 32);
            O[ds] = __builtin_amdgcn_mfma_f32_16x16x32_bf16(A1, vf0, O[ds], 0, 0, 0);
            O[ds] = __builtin_amdgcn_mfma_f32_16x16x32_bf16(A2, vf1, O[ds], 0, 0, 0);
        }
#pragma unroll
        for (int i = 0; i < 8; ++i) ka[i] = kb[i];
    }

    // per-wave partials to LDS
#pragma unroll
    for (int ds = 0; ds < 4; ++ds)
#pragma unroll
        for (int r = 0; r < 4; ++r)
            Ow[w][g4 + r][ds * 16 + li] = O[ds][r];
    if (l < 16) mwS[w][l] = m_run;
    if (li == 0) {
#pragma unroll
        for (int r = 0; r < 4; ++r) lwS[w][g4 + r] = l4[r];
    }
    __syncthreads();

    // combine 4 wave partials; thread -> (q = t>>4, d4 = (t&15)*4)
    {
        const int qq = t >> 4;
        const int dd = (t & 15) * 4;
        float m0v = mwS[0][qq], m1v = mwS[1][qq], m2v = mwS[2][qq], m3v = mwS[3][qq];
        float mx = fmaxf(fmaxf(m0v, m1v), fmaxf(m2v, m3v));
        float c0 = ex2(m0v - mx), c1 = ex2(m1v - mx);
        float c2 = ex2(m2v - mx), c3 = ex2(m3v - mx);
        float L = lwS[0][qq]*c0 + lwS[1][qq]*c1 + lwS[2][qq]*c2 + lwS[3][qq]*c3;
        float4 o0 = *reinterpret_cast<const float4*>(&Ow[0][qq][dd]);
        float4 o1 = *reinterpret_cast<const float4*>(&Ow[1][qq][dd]);
        float4 o2 = *reinterpret_cast<const float4*>(&Ow[2][qq][dd]);
        float4 o3 = *reinterpret_cast<const float4*>(&Ow[3][qq][dd]);
        float rx = c0*o0.x + c1*o1.x + c2*o2.x + c3*o3.x;
        float ry = c0*o0.y + c1*o1.y + c2*o2.y + c3*o3.y;
        float rz = c0*o0.z + c1*o1.z + c2*o2.z + c3*o3.z;
        float rw = c0*o0.w + c1*o1.w + c2*o2.w + c3*o3.w;
        if (nc == 1) {
            const float rl = (L > 0.f) ? 1.f / L : 0.f;
            rx *= rl; ry *= rl; rz *= rl; rw *= rl;
            const long row = (long)(b * SEQ + q0 + qq);
            if (flag) {
                uint2 st = make_uint2(pkbf(rx, ry), pkbf(rz, rw));
                *reinterpret_cast<uint2*>((u16*)out + row * HD + dd) = st;
            } else {
                *reinterpret_cast<float4*>((float*)out + row * HD + dd) =
                    make_float4(rx, ry, rz, rw);
            }
        } else {
            const long slot = ((long)(b * 128 + (qt16 - 128)) * 2 + c) * PSLOT;
            *reinterpret_cast<float4*>(&part[slot + qq * 64 + dd]) =
                make_float4(rx, ry, rz, rw);
            if ((t & 15) == 0) {
                part[slot + 1024 + qq] = mx;
                part[slot + 1040 + qq] = L;
            }
        }
    }
}

// ---------------- merge split-K partials (qt16 >= 128) ----------------
__global__ __launch_bounds__(256) void merge_kernel(
    const u32* __restrict__ xs, const float* __restrict__ part,
    void* __restrict__ out)
{
    const int flag = sniff_bf16(xs);
    const int bid = blockIdx.x;         // 512
    const int b    = bid & 3;
    const int qt16 = 128 + (bid >> 2);
    const int t  = threadIdx.x;
    const int qq = t >> 4;
    const int dd = (t & 15) * 4;
    const long s0 = ((long)(b * 128 + (qt16 - 128)) * 2) * PSLOT;
    const long s1 = s0 + PSLOT;
    float m0 = part[s0 + 1024 + qq], l0 = part[s0 + 1040 + qq];
    float m1 = part[s1 + 1024 + qq], l1 = part[s1 + 1040 + qq];
    float mx = fmaxf(m0, m1);
    float c0 = ex2(m0 - mx), c1 = ex2(m1 - mx);
    float L  = l0 * c0 + l1 * c1;
    float rl = (L > 0.f) ? 1.f / L : 0.f;
    float4 o0 = *reinterpret_cast<const float4*>(&part[s0 + qq * 64 + dd]);
    float4 o1 = *reinterpret_cast<const float4*>(&part[s1 + qq * 64 + dd]);
    float rx = (c0*o0.x + c1*o1.x) * rl;
    float ry = (c0*o0.y + c1*o1.y) * rl;
    float rz = (c0*o0.z + c1*o1.z) * rl;
    float rw = (c0*o0.w + c1*o1.w) * rl;
    const long row = (long)(b * SEQ + qt16 * 16 + qq);
    if (flag) {
        uint2 st = make_uint2(pkbf(rx, ry), pkbf(rz, rw));
        *reinterpret_cast<uint2*>((u16*)out + row * HD + dd) = st;
    } else {
        *reinterpret_cast<float4*>((float*)out + row * HD + dd) =
            make_float4(rx, ry, rz, rw);
    }
}

extern "C" void kernel_launch(void* const* d_in, const int* in_sizes, int n_in,
                              void* d_out, int out_size, void* d_ws, size_t ws_size,
                              hipStream_t stream) {
    const void* x   = d_in[0];
    const int* mask = (const int*)d_in[1];
    const void* wq  = d_in[2];
    const void* wk  = d_in[3];
    const void* wv  = d_in[4];
    const u32* xs   = (const u32*)x;

    u16* q    = (u16*)d_ws;
    u16* k    = q  + (long)NROW * HD;
    u16* vT   = k  + (long)NROW * HD;
    u16* wcat = vT + (long)NROW * HD;
    u32* mb   = (u32*)(wcat + (long)192 * DIM);
    float* part = (float*)((char*)mb + 4096);   // 1024 slots * PSLOT floats

    prep_kernel <<<578, 256, 0, stream>>>(xs, wq, wk, wv, mask, wcat, mb);
    qkv_kernel  <<<NROW / 32, 256, 0, stream>>>(x, wcat, q, k, vT);
    attn_kernel <<<4 * 384, 256, 0, stream>>>(xs, q, k, vT, mb, part, d_out);
    merge_kernel<<<512, 256, 0, stream>>>(xs, part, d_out);
}